// Round 1
// baseline (281.520 us; speedup 1.0000x reference)
//
#include <hip/hip_runtime.h>
#include <math.h>

// FeatureNormalizedMSE: NaN-omitted, feature-weighted, per-sample-normalized MSE.
// B=2048 samples, F=16384 features. Memory-bound: 2 x 134 MB fp32 reads.
// Strategy: 1 block (256 thr) per sample; float4 vector loads; wave64 shuffle
// reduction -> LDS cross-wave reduction -> one atomicAdd per block.

#define B_SAMPLES 2048
#define F_FEATURES 16384
#define THREADS 256
#define VEC_PER_THREAD (F_FEATURES / 4 / THREADS)  // 16 float4 loads per thread

__global__ __launch_bounds__(THREADS) void fnmse_kernel(
    const float* __restrict__ output,
    const float* __restrict__ target,
    const float* __restrict__ fw,
    float* __restrict__ out)
{
    const int b = blockIdx.x;
    const int tid = threadIdx.x;

    const float4* __restrict__ out4 = (const float4*)(output + (size_t)b * F_FEATURES);
    const float4* __restrict__ tgt4 = (const float4*)(target + (size_t)b * F_FEATURES);
    const float4* __restrict__ fw4  = (const float4*)fw;

    float sumsq = 0.0f;
    float cnt   = 0.0f;

    #pragma unroll
    for (int i = 0; i < VEC_PER_THREAD; ++i) {
        const int v = i * THREADS + tid;          // coalesced: lane stride 16 B
        float4 o = out4[v];
        float4 t = tgt4[v];
        float4 w = fw4[v];

        {
            const bool m = !isnan(t.x);
            const float r = m ? (t.x - o.x) * w.x : 0.0f;
            sumsq = fmaf(r, r, sumsq);
            cnt += m ? 1.0f : 0.0f;
        }
        {
            const bool m = !isnan(t.y);
            const float r = m ? (t.y - o.y) * w.y : 0.0f;
            sumsq = fmaf(r, r, sumsq);
            cnt += m ? 1.0f : 0.0f;
        }
        {
            const bool m = !isnan(t.z);
            const float r = m ? (t.z - o.z) * w.z : 0.0f;
            sumsq = fmaf(r, r, sumsq);
            cnt += m ? 1.0f : 0.0f;
        }
        {
            const bool m = !isnan(t.w);
            const float r = m ? (t.w - o.w) * w.w : 0.0f;
            sumsq = fmaf(r, r, sumsq);
            cnt += m ? 1.0f : 0.0f;
        }
    }

    // wave64 butterfly reduce
    #pragma unroll
    for (int off = 32; off > 0; off >>= 1) {
        sumsq += __shfl_down(sumsq, off, 64);
        cnt   += __shfl_down(cnt,   off, 64);
    }

    __shared__ float s_sq[THREADS / 64];
    __shared__ float s_ct[THREADS / 64];
    const int wave = tid >> 6;
    const int lane = tid & 63;
    if (lane == 0) { s_sq[wave] = sumsq; s_ct[wave] = cnt; }
    __syncthreads();

    if (tid == 0) {
        float sq = s_sq[0] + s_sq[1] + s_sq[2] + s_sq[3];
        float ct = s_ct[0] + s_ct[1] + s_ct[2] + s_ct[3];
        atomicAdd(out, sq / ct);  // device-scope by default on CDNA4
    }
}

extern "C" void kernel_launch(void* const* d_in, const int* in_sizes, int n_in,
                              void* d_out, int out_size, void* d_ws, size_t ws_size,
                              hipStream_t stream) {
    const float* output = (const float*)d_in[0];  // [B,C,H,W] fp32
    const float* target = (const float*)d_in[1];  // [B,C,H,W] fp32 with NaNs
    // d_in[2] = e_exp (unused), d_in[3] = sample_weight (unused)
    const float* fw     = (const float*)d_in[4];  // [F,1] fp32
    float* out = (float*)d_out;

    // d_out is re-poisoned to 0xAA before every timed replay — zero it on-stream.
    hipMemsetAsync(out, 0, sizeof(float), stream);

    fnmse_kernel<<<B_SAMPLES, THREADS, 0, stream>>>(output, target, fw, out);
}

// Round 2
// 273.591 us; speedup vs baseline: 1.0290x; 1.0290x over previous
//
#include <hip/hip_runtime.h>
#include <math.h>

// FeatureNormalizedMSE: NaN-omitted, feature-weighted, per-sample-normalized MSE.
// B=2048, F=16384. Memory-bound (268 MB fp32 reads, ~half L3-resident).
// R2 strategy: 4 chunks/sample -> 8192 blocks (4x oversubscription so L3-fast
// blocks retire and slots refill), 12 float4 loads batched up-front per thread
// for MLP. Pass 1: atomicAdd per-sample {sumsq,cnt} into ws. Pass 2: tiny
// reduce kernel computes sum(sumsq/cnt).

#define B_SAMPLES 2048
#define F_FEATURES 16384
#define THREADS 256
#define CHUNKS 4
#define F_CHUNK (F_FEATURES / CHUNKS)          // 4096 floats = 1024 float4
#define V_PER_THREAD (F_CHUNK / 4 / THREADS)   // 4 float4 per thread per stream

__global__ __launch_bounds__(THREADS) void fnmse_partial(
    const float* __restrict__ output,
    const float* __restrict__ target,
    const float* __restrict__ fw,
    float* __restrict__ ws_sq,
    float* __restrict__ ws_ct)
{
    const int b = blockIdx.x >> 2;         // sample
    const int c = blockIdx.x & 3;          // chunk within sample
    const int tid = threadIdx.x;

    const float4* __restrict__ o4 = (const float4*)(output + (size_t)b * F_FEATURES + c * F_CHUNK);
    const float4* __restrict__ t4 = (const float4*)(target + (size_t)b * F_FEATURES + c * F_CHUNK);
    const float4* __restrict__ w4 = (const float4*)(fw + c * F_CHUNK);

    // Batch ALL loads first: 12 independent 16B loads in flight per thread.
    float4 o[V_PER_THREAD], t[V_PER_THREAD], w[V_PER_THREAD];
    #pragma unroll
    for (int k = 0; k < V_PER_THREAD; ++k) {
        const int v = k * THREADS + tid;   // coalesced
        o[k] = o4[v];
        t[k] = t4[v];
        w[k] = w4[v];
    }

    float sumsq = 0.0f;
    float cnt   = 0.0f;
    #pragma unroll
    for (int k = 0; k < V_PER_THREAD; ++k) {
        {
            const bool m = !isnan(t[k].x);
            const float r = m ? (t[k].x - o[k].x) * w[k].x : 0.0f;
            sumsq = fmaf(r, r, sumsq); cnt += m ? 1.0f : 0.0f;
        }
        {
            const bool m = !isnan(t[k].y);
            const float r = m ? (t[k].y - o[k].y) * w[k].y : 0.0f;
            sumsq = fmaf(r, r, sumsq); cnt += m ? 1.0f : 0.0f;
        }
        {
            const bool m = !isnan(t[k].z);
            const float r = m ? (t[k].z - o[k].z) * w[k].z : 0.0f;
            sumsq = fmaf(r, r, sumsq); cnt += m ? 1.0f : 0.0f;
        }
        {
            const bool m = !isnan(t[k].w);
            const float r = m ? (t[k].w - o[k].w) * w[k].w : 0.0f;
            sumsq = fmaf(r, r, sumsq); cnt += m ? 1.0f : 0.0f;
        }
    }

    // wave64 butterfly reduce
    #pragma unroll
    for (int off = 32; off > 0; off >>= 1) {
        sumsq += __shfl_down(sumsq, off, 64);
        cnt   += __shfl_down(cnt,   off, 64);
    }

    __shared__ float s_sq[THREADS / 64];
    __shared__ float s_ct[THREADS / 64];
    const int wave = tid >> 6;
    const int lane = tid & 63;
    if (lane == 0) { s_sq[wave] = sumsq; s_ct[wave] = cnt; }
    __syncthreads();

    if (tid == 0) {
        const float sq = s_sq[0] + s_sq[1] + s_sq[2] + s_sq[3];
        const float ct = s_ct[0] + s_ct[1] + s_ct[2] + s_ct[3];
        atomicAdd(&ws_sq[b], sq);
        atomicAdd(&ws_ct[b], ct);
    }
}

// Pass 2: out[0] = sum_b ws_sq[b] / ws_ct[b]. One block.
__global__ __launch_bounds__(THREADS) void fnmse_finalize(
    const float* __restrict__ ws_sq,
    const float* __restrict__ ws_ct,
    float* __restrict__ out)
{
    const int tid = threadIdx.x;
    float acc = 0.0f;
    #pragma unroll
    for (int s = 0; s < B_SAMPLES / THREADS; ++s) {
        const int b = s * THREADS + tid;
        acc += ws_sq[b] / ws_ct[b];
    }
    #pragma unroll
    for (int off = 32; off > 0; off >>= 1)
        acc += __shfl_down(acc, off, 64);

    __shared__ float s_a[THREADS / 64];
    const int wave = tid >> 6;
    const int lane = tid & 63;
    if (lane == 0) s_a[wave] = acc;
    __syncthreads();
    if (tid == 0) out[0] = s_a[0] + s_a[1] + s_a[2] + s_a[3];
}

extern "C" void kernel_launch(void* const* d_in, const int* in_sizes, int n_in,
                              void* d_out, int out_size, void* d_ws, size_t ws_size,
                              hipStream_t stream) {
    const float* output = (const float*)d_in[0];  // [B,C,H,W] fp32
    const float* target = (const float*)d_in[1];  // [B,C,H,W] fp32 with NaNs
    // d_in[2] = e_exp (unused), d_in[3] = sample_weight (unused)
    const float* fw     = (const float*)d_in[4];  // [F,1] fp32
    float* out = (float*)d_out;

    float* ws_sq = (float*)d_ws;                  // [B]
    float* ws_ct = ws_sq + B_SAMPLES;             // [B]

    // ws is re-poisoned to 0xAA before every replay — zero the 16 KB we use.
    hipMemsetAsync(d_ws, 0, 2 * B_SAMPLES * sizeof(float), stream);

    fnmse_partial<<<B_SAMPLES * CHUNKS, THREADS, 0, stream>>>(output, target, fw, ws_sq, ws_ct);
    fnmse_finalize<<<1, THREADS, 0, stream>>>(ws_sq, ws_ct, out);
}

// Round 4
// 255.597 us; speedup vs baseline: 1.1014x; 1.0704x over previous
//
#include <hip/hip_runtime.h>
#include <math.h>

// FeatureNormalizedMSE: NaN-omitted, feature-weighted, per-sample-normalized MSE.
// B=2048, F=16384. Memory-bound: 268 MB fp32 reads.
// R4 = R3 with the compile fix: __builtin_nontemporal_load requires a clang
// native vector type, not HIP_vector_type<float,4>. Theory unchanged:
// R2 showed a hard ~2.8 TB/s aggregate wall with FETCH_SIZE==one array;
// nt loads bypass L3 write-allocation so fills stop competing with hits.
// Plus explicit 2-stage software pipeline against vmcnt(0) serialization.

#define B_SAMPLES 2048
#define F_FEATURES 16384
#define THREADS 256
#define CHUNKS 4
#define F_CHUNK (F_FEATURES / CHUNKS)          // 4096 floats = 1024 float4
#define V_PER_THREAD (F_CHUNK / 4 / THREADS)   // 4 float4 per thread per stream

typedef float fx4 __attribute__((ext_vector_type(4)));

__device__ __forceinline__ void accum(const fx4 t, const fx4 o, const fx4 w,
                                      float& sumsq, float& cnt) {
    #pragma unroll
    for (int j = 0; j < 4; ++j) {
        const bool m = !isnan(t[j]);
        const float r = m ? (t[j] - o[j]) * w[j] : 0.0f;
        sumsq = fmaf(r, r, sumsq);
        cnt += m ? 1.0f : 0.0f;
    }
}

__global__ __launch_bounds__(THREADS) void fnmse_partial(
    const float* __restrict__ output,
    const float* __restrict__ target,
    const float* __restrict__ fw,
    float* __restrict__ ws_sq,
    float* __restrict__ ws_ct)
{
    const int b = blockIdx.x >> 2;         // sample
    const int c = blockIdx.x & 3;          // chunk within sample
    const int tid = threadIdx.x;

    const fx4* __restrict__ o4 = (const fx4*)(output + (size_t)b * F_FEATURES + c * F_CHUNK);
    const fx4* __restrict__ t4 = (const fx4*)(target + (size_t)b * F_FEATURES + c * F_CHUNK);
    const fx4* __restrict__ w4 = (const fx4*)(fw + c * F_CHUNK);

    float sumsq = 0.0f;
    float cnt   = 0.0f;

    // 2-stage software pipeline: prefetch k+1 while accumulating k.
    fx4 o_c = __builtin_nontemporal_load(o4 + tid);
    fx4 t_c = __builtin_nontemporal_load(t4 + tid);
    fx4 w_c = w4[tid];                     // fw is hot/small — normal cached load

    #pragma unroll
    for (int k = 0; k < V_PER_THREAD; ++k) {
        fx4 o_n, t_n, w_n;
        if (k + 1 < V_PER_THREAD) {
            const int v = (k + 1) * THREADS + tid;   // coalesced
            o_n = __builtin_nontemporal_load(o4 + v);
            t_n = __builtin_nontemporal_load(t4 + v);
            w_n = w4[v];
        }
        accum(t_c, o_c, w_c, sumsq, cnt);
        o_c = o_n; t_c = t_n; w_c = w_n;
    }

    // wave64 butterfly reduce
    #pragma unroll
    for (int off = 32; off > 0; off >>= 1) {
        sumsq += __shfl_down(sumsq, off, 64);
        cnt   += __shfl_down(cnt,   off, 64);
    }

    __shared__ float s_sq[THREADS / 64];
    __shared__ float s_ct[THREADS / 64];
    const int wave = tid >> 6;
    const int lane = tid & 63;
    if (lane == 0) { s_sq[wave] = sumsq; s_ct[wave] = cnt; }
    __syncthreads();

    if (tid == 0) {
        const float sq = s_sq[0] + s_sq[1] + s_sq[2] + s_sq[3];
        const float ct = s_ct[0] + s_ct[1] + s_ct[2] + s_ct[3];
        atomicAdd(&ws_sq[b], sq);
        atomicAdd(&ws_ct[b], ct);
    }
}

// Pass 2: out[0] = sum_b ws_sq[b] / ws_ct[b]. One block.
__global__ __launch_bounds__(THREADS) void fnmse_finalize(
    const float* __restrict__ ws_sq,
    const float* __restrict__ ws_ct,
    float* __restrict__ out)
{
    const int tid = threadIdx.x;
    float acc = 0.0f;
    #pragma unroll
    for (int s = 0; s < B_SAMPLES / THREADS; ++s) {
        const int b = s * THREADS + tid;
        acc += ws_sq[b] / ws_ct[b];
    }
    #pragma unroll
    for (int off = 32; off > 0; off >>= 1)
        acc += __shfl_down(acc, off, 64);

    __shared__ float s_a[THREADS / 64];
    const int wave = tid >> 6;
    const int lane = tid & 63;
    if (lane == 0) s_a[wave] = acc;
    __syncthreads();
    if (tid == 0) out[0] = s_a[0] + s_a[1] + s_a[2] + s_a[3];
}

extern "C" void kernel_launch(void* const* d_in, const int* in_sizes, int n_in,
                              void* d_out, int out_size, void* d_ws, size_t ws_size,
                              hipStream_t stream) {
    const float* output = (const float*)d_in[0];  // [B,C,H,W] fp32
    const float* target = (const float*)d_in[1];  // [B,C,H,W] fp32 with NaNs
    // d_in[2] = e_exp (unused), d_in[3] = sample_weight (unused)
    const float* fw     = (const float*)d_in[4];  // [F,1] fp32
    float* out = (float*)d_out;

    float* ws_sq = (float*)d_ws;                  // [B]
    float* ws_ct = ws_sq + B_SAMPLES;             // [B]

    // ws is re-poisoned to 0xAA before every replay — zero the 16 KB we use.
    (void)hipMemsetAsync(d_ws, 0, 2 * B_SAMPLES * sizeof(float), stream);

    fnmse_partial<<<B_SAMPLES * CHUNKS, THREADS, 0, stream>>>(output, target, fw, ws_sq, ws_ct);
    fnmse_finalize<<<1, THREADS, 0, stream>>>(ws_sq, ws_ct, out);
}